// Round 1
// baseline (1491.099 us; speedup 1.0000x reference)
//
#include <hip/hip_runtime.h>
#include <stdint.h>

#define NVN 100000
#define NCN 50000
#define NE  800000
#define H   128

static __device__ __forceinline__ float wredsum(float v) {
#pragma unroll
  for (int off = 32; off > 0; off >>= 1) v += __shfl_xor(v, off, 64);
  return v;
}
static __device__ __forceinline__ float sigmoidf(float x) { return 1.0f / (1.0f + __expf(-x)); }

// ---------------- init: h = LN(relu(x @ W + b)) ----------------
__global__ __launch_bounds__(256) void k_init_var(const float* __restrict__ xv,
    const float* __restrict__ w, const float* __restrict__ b,
    const float* __restrict__ g, const float* __restrict__ bb, float* __restrict__ hv) {
  int wid = (blockIdx.x * 256 + threadIdx.x) >> 6;
  int lane = threadIdx.x & 63;
  if (wid >= NVN) return;
  float x0 = xv[wid*4+0], x1 = xv[wid*4+1], x2 = xv[wid*4+2], x3 = xv[wid*4+3];
  int c0 = lane, c1 = lane + 64;
  float v0 = b[c0] + x0*w[c0] + x1*w[H+c0] + x2*w[2*H+c0] + x3*w[3*H+c0];
  float v1 = b[c1] + x0*w[c1] + x1*w[H+c1] + x2*w[2*H+c1] + x3*w[3*H+c1];
  v0 = fmaxf(v0, 0.f); v1 = fmaxf(v1, 0.f);
  float mu = wredsum(v0 + v1) * (1.0f/H);
  float d0 = v0 - mu, d1 = v1 - mu;
  float var = wredsum(d0*d0 + d1*d1) * (1.0f/H);
  float r = rsqrtf(var + 1e-5f);
  hv[(size_t)wid*H + c0] = d0*r*g[c0] + bb[c0];
  hv[(size_t)wid*H + c1] = d1*r*g[c1] + bb[c1];
}

__global__ __launch_bounds__(256) void k_init_con(const float* __restrict__ xc,
    const float* __restrict__ w, const float* __restrict__ b,
    const float* __restrict__ g, const float* __restrict__ bb, float* __restrict__ hc) {
  int wid = (blockIdx.x * 256 + threadIdx.x) >> 6;
  int lane = threadIdx.x & 63;
  if (wid >= NCN) return;
  float x = xc[wid];
  int c0 = lane, c1 = lane + 64;
  float v0 = fmaxf(b[c0] + x*w[c0], 0.f);
  float v1 = fmaxf(b[c1] + x*w[c1], 0.f);
  float mu = wredsum(v0 + v1) * (1.0f/H);
  float d0 = v0 - mu, d1 = v1 - mu;
  float var = wredsum(d0*d0 + d1*d1) * (1.0f/H);
  float r = rsqrtf(var + 1e-5f);
  hc[(size_t)wid*H + c0] = d0*r*g[c0] + bb[c0];
  hc[(size_t)wid*H + c1] = d1*r*g[c1] + bb[c1];
}

// ---------------- weight fusion: Wf = Wmsg @ Wupd[:H], bfu = bmsg @ Wupd[:H] ----------------
__global__ void k_fuse_w(const float* __restrict__ wm, const float* __restrict__ wu,
                         float* __restrict__ wf) {
  int idx = blockIdx.x*256 + threadIdx.x;   // 16384
  int i = idx >> 7, j = idx & 127;
  float a = 0.f;
  for (int k = 0; k < H; ++k) a = fmaf(wm[i*H+k], wu[k*H+j], a);
  wf[idx] = a;
}
__global__ void k_fuse_b(const float* __restrict__ bm, const float* __restrict__ wu,
                         float* __restrict__ bf) {
  int j = threadIdx.x;
  float a = 0.f;
  for (int k = 0; k < H; ++k) a = fmaf(bm[k], wu[k*H+j], a);
  bf[j] = a;
}

// ---------------- CSR build ----------------
__global__ void k_count(const int* __restrict__ dc, const int* __restrict__ dv,
                        int* __restrict__ cnt_c, int* __restrict__ cnt_v) {
  for (int e = blockIdx.x*blockDim.x + threadIdx.x; e < NE; e += gridDim.x*blockDim.x) {
    atomicAdd(&cnt_c[dc[e]], 1);
    atomicAdd(&cnt_v[dv[e]], 1);
  }
}
__global__ __launch_bounds__(256) void k_scan1(const int* __restrict__ in, int* __restrict__ out,
                                               int* __restrict__ aux, int n) {
  __shared__ int s[256];
  int t = threadIdx.x, i = blockIdx.x*256 + t;
  int v = (i < n) ? in[i] : 0;
  s[t] = v; __syncthreads();
  for (int off = 1; off < 256; off <<= 1) {
    int x = (t >= off) ? s[t - off] : 0;
    __syncthreads();
    s[t] += x;
    __syncthreads();
  }
  if (i < n) out[i] = s[t] - v;          // exclusive, local
  if (t == 255) aux[blockIdx.x] = s[255];
}
__global__ __launch_bounds__(1024) void k_scan2(int* __restrict__ aux, int nb) {
  __shared__ int s[1024];
  int t = threadIdx.x;
  int v = (t < nb) ? aux[t] : 0;
  s[t] = v; __syncthreads();
  for (int off = 1; off < 1024; off <<= 1) {
    int x = (t >= off) ? s[t-off] : 0;
    __syncthreads();
    s[t] += x;
    __syncthreads();
  }
  if (t < nb) aux[t] = s[t] - v;         // exclusive block sums
}
__global__ __launch_bounds__(256) void k_scan3(int* __restrict__ out, const int* __restrict__ aux,
                                               int n, int total) {
  int i = blockIdx.x*256 + threadIdx.x;
  if (i < n) out[i] += aux[blockIdx.x];
  if (i == 0) out[n] = total;
}
__global__ void k_scatter(const int* __restrict__ sc, const int* __restrict__ dc,
                          const int* __restrict__ sv, const int* __restrict__ dv,
                          const int* __restrict__ off_c, int* __restrict__ cur_c, int* __restrict__ lst_c,
                          const int* __restrict__ off_v, int* __restrict__ cur_v, int* __restrict__ lst_v) {
  for (int e = blockIdx.x*blockDim.x + threadIdx.x; e < NE; e += gridDim.x*blockDim.x) {
    int d = dc[e]; int p = atomicAdd(&cur_c[d], 1); lst_c[off_c[d] + p] = sc[e];
    d = dv[e];     p = atomicAdd(&cur_v[d], 1);     lst_v[off_v[d] + p] = sv[e];
  }
}

// ---------------- gather: out[n] = (sum_{e in CSR[n]} tab[src_e]) / (deg + 1e-6) ----------------
__global__ __launch_bounds__(256) void k_gather(const float* __restrict__ tab,
    const int* __restrict__ off, const int* __restrict__ lst,
    float* __restrict__ out, int n) {
  int wid = (blockIdx.x * 256 + threadIdx.x) >> 6;
  int lane = threadIdx.x & 63;
  if (wid >= n) return;
  int s0 = off[wid], s1 = off[wid+1];
  float a0 = 0.f, a1 = 0.f;
  for (int p = s0; p < s1; ++p) {
    int src = lst[p];
    const float* row = tab + (size_t)src * H;
    a0 += row[lane]; a1 += row[lane+64];
  }
  float inv = 1.0f / ((float)(s1 - s0) + 1e-6f);
  out[(size_t)wid*H + lane]      = a0 * inv;
  out[(size_t)wid*H + lane + 64] = a1 * inv;
}

// ---------------- generic row matmul: OUT (+)= IN @ W, W(128x128) as bf16 in LDS ----------------
template <int ACC>
__global__ __launch_bounds__(256) void k_matmul(const float* __restrict__ IN,
    const float* __restrict__ Wg, float* __restrict__ OUT, int n) {
  __shared__ unsigned short Wl[H*H];     // bf16 bits, 32KB
  __shared__ float rowbuf[4][2][H];      // 4KB
  const int tid = threadIdx.x, wv = tid >> 6, lane = tid & 63;
  for (int i = tid; i < H*H; i += 256) {
    unsigned int u = __float_as_uint(Wg[i]);
    Wl[i] = (unsigned short)((u + 0x7FFFu + ((u >> 16) & 1u)) >> 16);  // RNE to bf16
  }
  __syncthreads();
  const int base = blockIdx.x * 64 + wv * 16;
  for (int rr = 0; rr < 16; rr += 2) {
    int r0 = base + rr, r1 = r0 + 1;
    if (r0 < n) ((float2*)rowbuf[wv][0])[lane] = ((const float2*)(IN + (size_t)r0*H))[lane];
    if (r1 < n) ((float2*)rowbuf[wv][1])[lane] = ((const float2*)(IN + (size_t)r1*H))[lane];
    __syncthreads();
    float acc00 = 0.f, acc01 = 0.f, acc10 = 0.f, acc11 = 0.f;
    const uint32_t* Wp = (const uint32_t*)Wl;           // Wp[k*64+l] = cols {2l,2l+1} of row k
    const float2* rb0 = (const float2*)rowbuf[wv][0];
    const float2* rb1 = (const float2*)rowbuf[wv][1];
#pragma unroll 8
    for (int k = 0; k < H; k += 2) {
      float2 a0 = rb0[k >> 1];
      float2 a1 = rb1[k >> 1];
      uint32_t wp0 = Wp[k*64 + lane];
      uint32_t wp1 = Wp[(k+1)*64 + lane];
      float w00 = __uint_as_float(wp0 << 16);
      float w01 = __uint_as_float(wp0 & 0xFFFF0000u);
      float w10 = __uint_as_float(wp1 << 16);
      float w11 = __uint_as_float(wp1 & 0xFFFF0000u);
      acc00 = fmaf(a0.x, w00, acc00); acc01 = fmaf(a0.x, w01, acc01);
      acc10 = fmaf(a1.x, w00, acc10); acc11 = fmaf(a1.x, w01, acc11);
      acc00 = fmaf(a0.y, w10, acc00); acc01 = fmaf(a0.y, w11, acc01);
      acc10 = fmaf(a1.y, w10, acc10); acc11 = fmaf(a1.y, w11, acc11);
    }
    __syncthreads();
    if (r0 < n) {
      float2* o = (float2*)(OUT + (size_t)r0*H + 2*lane);
      if (ACC) { float2 pv = *o; pv.x += acc00; pv.y += acc01; *o = pv; }
      else *o = make_float2(acc00, acc01);
    }
    if (r1 < n) {
      float2* o = (float2*)(OUT + (size_t)r1*H + 2*lane);
      if (ACC) { float2 pv = *o; pv.x += acc10; pv.y += acc11; *o = pv; }
      else *o = make_float2(acc10, acc11);
    }
  }
}

// ---------------- con epilogue: con_new = LN(relu(pre + scale*bfu + clue*w_clue + bupd)) ----------------
__global__ __launch_bounds__(256) void k_con_epi(const float* __restrict__ t,
    const int* __restrict__ cnt, const float* __restrict__ xc,
    const float* __restrict__ bfu, const float* __restrict__ wu, const float* __restrict__ bu,
    const float* __restrict__ g, const float* __restrict__ bb, float* __restrict__ out) {
  int wid = (blockIdx.x*256 + threadIdx.x) >> 6, lane = threadIdx.x & 63;
  if (wid >= NCN) return;
  float cf = (float)cnt[wid];
  float scale = cf / (cf + 1e-6f);
  float clue = xc[wid];
  int c0 = lane, c1 = lane + 64;
  float v0 = t[(size_t)wid*H+c0] + scale*bfu[c0] + clue*wu[H*H + c0] + bu[c0];
  float v1 = t[(size_t)wid*H+c1] + scale*bfu[c1] + clue*wu[H*H + c1] + bu[c1];
  v0 = fmaxf(v0, 0.f); v1 = fmaxf(v1, 0.f);
  float mu = wredsum(v0 + v1) * (1.0f/H);
  float d0 = v0 - mu, d1 = v1 - mu;
  float var = wredsum(d0*d0 + d1*d1) * (1.0f/H);
  float r = rsqrtf(var + 1e-5f);
  out[(size_t)wid*H + c0] = d0*r*g[c0] + bb[c0];
  out[(size_t)wid*H + c1] = d1*r*g[c1] + bb[c1];
}

// ---------------- var epilogue: var_new = LN(relu(pre + scale*bc2v)) ----------------
__global__ __launch_bounds__(256) void k_var_epi(const float* __restrict__ t,
    const int* __restrict__ cnt, const float* __restrict__ bc,
    const float* __restrict__ g, const float* __restrict__ bb, float* __restrict__ out) {
  int wid = (blockIdx.x*256 + threadIdx.x) >> 6, lane = threadIdx.x & 63;
  if (wid >= NVN) return;
  float cf = (float)cnt[wid];
  float scale = cf / (cf + 1e-6f);
  int c0 = lane, c1 = lane + 64;
  float v0 = fmaxf(t[(size_t)wid*H+c0] + scale*bc[c0], 0.f);
  float v1 = fmaxf(t[(size_t)wid*H+c1] + scale*bc[c1], 0.f);
  float mu = wredsum(v0 + v1) * (1.0f/H);
  float d0 = v0 - mu, d1 = v1 - mu;
  float var = wredsum(d0*d0 + d1*d1) * (1.0f/H);
  float r = rsqrtf(var + 1e-5f);
  out[(size_t)wid*H + c0] = d0*r*g[c0] + bb[c0];
  out[(size_t)wid*H + c1] = d1*r*g[c1] + bb[c1];
}

// ---------------- gate: h = sig(t + gb)*new + (1-sig)*h ----------------
__global__ __launch_bounds__(256) void k_gate(const float* __restrict__ t, const float* __restrict__ nw,
    float* __restrict__ hcur, const float* __restrict__ gb, int n4) {
  int i = blockIdx.x*256 + threadIdx.x;
  if (i >= n4) return;
  float4 tv = ((const float4*)t)[i];
  float4 nv = ((const float4*)nw)[i];
  float4 hv = ((const float4*)hcur)[i];
  float4 gv = ((const float4*)gb)[i & 31];
  float g0 = sigmoidf(tv.x + gv.x), g1 = sigmoidf(tv.y + gv.y);
  float g2 = sigmoidf(tv.z + gv.z), g3 = sigmoidf(tv.w + gv.w);
  float4 o;
  o.x = g0*nv.x + (1.f-g0)*hv.x;
  o.y = g1*nv.y + (1.f-g1)*hv.y;
  o.z = g2*nv.z + (1.f-g2)*hv.z;
  o.w = g3*nv.w + (1.f-g3)*hv.w;
  ((float4*)hcur)[i] = o;
}

extern "C" void kernel_launch(void* const* d_in, const int* in_sizes, int n_in,
                              void* d_out, int out_size, void* d_ws, size_t ws_size,
                              hipStream_t stream) {
  const float* x_var   = (const float*)d_in[0];
  const float* x_con   = (const float*)d_in[1];
  const int*   evc_src = (const int*)d_in[2];
  const int*   evc_dst = (const int*)d_in[3];
  const int*   ecv_src = (const int*)d_in[4];
  const int*   ecv_dst = (const int*)d_in[5];
  const float* vproj_w = (const float*)d_in[6];
  const float* vproj_b = (const float*)d_in[7];
  const float* cproj_w = (const float*)d_in[8];
  const float* cproj_b = (const float*)d_in[9];
  const float* wmsg    = (const float*)d_in[10];
  const float* bmsg    = (const float*)d_in[11];
  const float* wupd    = (const float*)d_in[12];
  const float* bupd    = (const float*)d_in[13];
  const float* v2c_ln_g = (const float*)d_in[14];
  const float* v2c_ln_b = (const float*)d_in[15];
  const float* wc2v    = (const float*)d_in[16];
  const float* bc2v    = (const float*)d_in[17];
  const float* c2v_ln_g = (const float*)d_in[18];
  const float* c2v_ln_b = (const float*)d_in[19];
  const float* vgate_w = (const float*)d_in[20];
  const float* vgate_b = (const float*)d_in[21];
  const float* cgate_w = (const float*)d_in[22];
  const float* cgate_b = (const float*)d_in[23];
  const float* var_ln_g = (const float*)d_in[24];
  const float* var_ln_b = (const float*)d_in[25];
  const float* con_ln_g = (const float*)d_in[26];
  const float* con_ln_b = (const float*)d_in[27];
  float* hv = (float*)d_out;

  char* p = (char*)d_ws;
  auto carve = [&](size_t bytes) { char* r = p; p += (bytes + 255) & ~(size_t)255; return r; };
  int* cnt_c = (int*)carve((size_t)NCN*4);
  int* cur_c = (int*)carve((size_t)NCN*4);
  int* cnt_v = (int*)carve((size_t)NVN*4);
  int* cur_v = (int*)carve((size_t)NVN*4);
  int* off_c = (int*)carve((size_t)(NCN+1)*4);
  int* off_v = (int*)carve((size_t)(NVN+1)*4);
  int* aux   = (int*)carve(1024*4);
  int* lst_c = (int*)carve((size_t)NE*4);
  int* lst_v = (int*)carve((size_t)NE*4);
  float* wf    = (float*)carve((size_t)H*H*4);
  float* bfu   = (float*)carve((size_t)H*4);
  float* t_c   = (float*)carve((size_t)NCN*H*4);
  float* c_new = (float*)carve((size_t)NCN*H*4);
  float* hc    = (float*)carve((size_t)NCN*H*4);
  float* t_v   = (float*)carve((size_t)NVN*H*4);
  float* v_new = (float*)carve((size_t)NVN*H*4);
  if ((size_t)(p - (char*)d_ws) > ws_size) return;  // workspace too small: bail cleanly

  hipMemsetAsync(cnt_c, 0, (size_t)NCN*4, stream);
  hipMemsetAsync(cur_c, 0, (size_t)NCN*4, stream);
  hipMemsetAsync(cnt_v, 0, (size_t)NVN*4, stream);
  hipMemsetAsync(cur_v, 0, (size_t)NVN*4, stream);

  k_fuse_w<<<64, 256, 0, stream>>>(wmsg, wupd, wf);
  k_fuse_b<<<1, 128, 0, stream>>>(bmsg, wupd, bfu);
  k_count<<<1024, 256, 0, stream>>>(evc_dst, ecv_dst, cnt_c, cnt_v);
  int nbc = (NCN + 255)/256, nbv = (NVN + 255)/256;
  k_scan1<<<nbc, 256, 0, stream>>>(cnt_c, off_c, aux, NCN);
  k_scan2<<<1, 1024, 0, stream>>>(aux, nbc);
  k_scan3<<<nbc, 256, 0, stream>>>(off_c, aux, NCN, NE);
  k_scan1<<<nbv, 256, 0, stream>>>(cnt_v, off_v, aux, NVN);
  k_scan2<<<1, 1024, 0, stream>>>(aux, nbv);
  k_scan3<<<nbv, 256, 0, stream>>>(off_v, aux, NVN, NE);
  k_scatter<<<1024, 256, 0, stream>>>(evc_src, evc_dst, ecv_src, ecv_dst,
                                      off_c, cur_c, lst_c, off_v, cur_v, lst_v);
  k_init_var<<<NVN/4, 256, 0, stream>>>(x_var, vproj_w, vproj_b, var_ln_g, var_ln_b, hv);
  k_init_con<<<NCN/4, 256, 0, stream>>>(x_con, cproj_w, cproj_b, con_ln_g, con_ln_b, hc);

  for (int r = 0; r < 2; ++r) {
    // ---- v2c ----
    k_gather<<<(NCN+3)/4, 256, 0, stream>>>(hv, off_c, lst_c, t_c, NCN);
    k_matmul<0><<<(NCN+63)/64, 256, 0, stream>>>(t_c, wf, t_c, NCN);           // pre = mean_hv @ Wf
    k_con_epi<<<(NCN+3)/4, 256, 0, stream>>>(t_c, cnt_c, x_con, bfu, wupd, bupd,
                                             v2c_ln_g, v2c_ln_b, c_new);
    k_matmul<0><<<(NCN+63)/64, 256, 0, stream>>>(hc, cgate_w, t_c, NCN);        // t = hc @ Gc1
    k_matmul<1><<<(NCN+63)/64, 256, 0, stream>>>(c_new, cgate_w + H*H, t_c, NCN); // t += c_new @ Gc2
    k_gate<<<(NCN*H/4 + 255)/256, 256, 0, stream>>>(t_c, c_new, hc, cgate_b, NCN*H/4);
    // ---- c2v ----
    k_gather<<<(NVN+3)/4, 256, 0, stream>>>(hc, off_v, lst_v, t_v, NVN);
    k_matmul<0><<<(NVN+63)/64, 256, 0, stream>>>(t_v, wc2v, t_v, NVN);          // pre2 = mean_hc @ Wc2v
    k_var_epi<<<(NVN+3)/4, 256, 0, stream>>>(t_v, cnt_v, bc2v, c2v_ln_g, c2v_ln_b, v_new);
    k_matmul<0><<<(NVN+63)/64, 256, 0, stream>>>(hv, vgate_w, t_v, NVN);        // t = hv @ Gv1
    k_matmul<1><<<(NVN+63)/64, 256, 0, stream>>>(v_new, vgate_w + H*H, t_v, NVN); // t += v_new @ Gv2
    k_gate<<<(NVN*H/4 + 255)/256, 256, 0, stream>>>(t_v, v_new, hv, vgate_b, NVN*H/4);
  }
}

// Round 7
// 1324.874 us; speedup vs baseline: 1.1255x; 1.1255x over previous
//
#include <hip/hip_runtime.h>
#include <stdint.h>

#define NVN 100000
#define NCN 50000
#define NE  800000
#define H   128

typedef __attribute__((ext_vector_type(8))) short bf16x8;
typedef __attribute__((ext_vector_type(4))) float f32x4;

static __device__ __forceinline__ float wredsum(float v) {
#pragma unroll
  for (int off = 32; off > 0; off >>= 1) v += __shfl_xor(v, off, 64);
  return v;
}
static __device__ __forceinline__ float sigmoidf(float x) { return 1.0f / (1.0f + __expf(-x)); }
static __device__ __forceinline__ unsigned short f2bf(float f) {
  unsigned int u = __float_as_uint(f);
  return (unsigned short)((u + 0x7FFFu + ((u >> 16) & 1u)) >> 16);  // RNE
}
static __device__ __forceinline__ short2 splitbf(float f) {
  unsigned short h = f2bf(f);
  float hf = __uint_as_float(((unsigned int)h) << 16);
  short2 r;
  r.x = (short)h;
  r.y = (short)f2bf(f - hf);
  return r;
}

// ---------------- init: h = LN(relu(x @ W + b)) ----------------
__global__ __launch_bounds__(256) void k_init_var(const float* __restrict__ xv,
    const float* __restrict__ w, const float* __restrict__ b,
    const float* __restrict__ g, const float* __restrict__ bb, float* __restrict__ hv) {
  int wid = (blockIdx.x * 256 + threadIdx.x) >> 6;
  int lane = threadIdx.x & 63;
  if (wid >= NVN) return;
  float x0 = xv[wid*4+0], x1 = xv[wid*4+1], x2 = xv[wid*4+2], x3 = xv[wid*4+3];
  int c0 = lane, c1 = lane + 64;
  float v0 = b[c0] + x0*w[c0] + x1*w[H+c0] + x2*w[2*H+c0] + x3*w[3*H+c0];
  float v1 = b[c1] + x0*w[c1] + x1*w[H+c1] + x2*w[2*H+c1] + x3*w[3*H+c1];
  v0 = fmaxf(v0, 0.f); v1 = fmaxf(v1, 0.f);
  float mu = wredsum(v0 + v1) * (1.0f/H);
  float d0 = v0 - mu, d1 = v1 - mu;
  float var = wredsum(d0*d0 + d1*d1) * (1.0f/H);
  float r = rsqrtf(var + 1e-5f);
  hv[(size_t)wid*H + c0] = d0*r*g[c0] + bb[c0];
  hv[(size_t)wid*H + c1] = d1*r*g[c1] + bb[c1];
}

__global__ __launch_bounds__(256) void k_init_con(const float* __restrict__ xc,
    const float* __restrict__ w, const float* __restrict__ b,
    const float* __restrict__ g, const float* __restrict__ bb, float* __restrict__ hc) {
  int wid = (blockIdx.x * 256 + threadIdx.x) >> 6;
  int lane = threadIdx.x & 63;
  if (wid >= NCN) return;
  float x = xc[wid];
  int c0 = lane, c1 = lane + 64;
  float v0 = fmaxf(b[c0] + x*w[c0], 0.f);
  float v1 = fmaxf(b[c1] + x*w[c1], 0.f);
  float mu = wredsum(v0 + v1) * (1.0f/H);
  float d0 = v0 - mu, d1 = v1 - mu;
  float var = wredsum(d0*d0 + d1*d1) * (1.0f/H);
  float r = rsqrtf(var + 1e-5f);
  hc[(size_t)wid*H + c0] = d0*r*g[c0] + bb[c0];
  hc[(size_t)wid*H + c1] = d1*r*g[c1] + bb[c1];
}

// ---------------- weight fusion ----------------
__global__ void k_fuse_w(const float* __restrict__ wm, const float* __restrict__ wu,
                         float* __restrict__ wf) {
  int idx = blockIdx.x*256 + threadIdx.x;   // 16384
  int i = idx >> 7, j = idx & 127;
  float a = 0.f;
  for (int k = 0; k < H; ++k) a = fmaf(wm[i*H+k], wu[k*H+j], a);
  wf[idx] = a;
}
__global__ void k_fuse_b(const float* __restrict__ bm, const float* __restrict__ wu,
                         float* __restrict__ bf) {
  int j = threadIdx.x;
  float a = 0.f;
  for (int k = 0; k < H; ++k) a = fmaf(bm[k], wu[k*H+j], a);
  bf[j] = a;
}

// ---------------- weight permutation into MFMA B-fragment order, hi+lo split ----------------
__global__ __launch_bounds__(256) void k_perm2(const float* __restrict__ W,
    unsigned short* __restrict__ Whi, unsigned short* __restrict__ Wlo, int K) {
  int idx = blockIdx.x*256 + threadIdx.x;
  if (idx >= K*H) return;
  int j = idx & 7, lane = (idx >> 3) & 63, ct = (idx >> 9) & 7, kb = idx >> 12;
  int k = kb*32 + (lane >> 4)*8 + j, c = ct*16 + (lane & 15);
  float w = W[k*H + c];
  unsigned short h = f2bf(w);
  float hf = __uint_as_float(((unsigned int)h) << 16);
  Whi[idx] = h;
  Wlo[idx] = f2bf(w - hf);
}

// ---------------- CSR build ----------------
__global__ void k_count(const int* __restrict__ dc, const int* __restrict__ dv,
                        int* __restrict__ cnt_c, int* __restrict__ cnt_v) {
  for (int e = blockIdx.x*blockDim.x + threadIdx.x; e < NE; e += gridDim.x*blockDim.x) {
    atomicAdd(&cnt_c[dc[e]], 1);
    atomicAdd(&cnt_v[dv[e]], 1);
  }
}
__global__ __launch_bounds__(256) void k_scan1(const int* __restrict__ in, int* __restrict__ out,
                                               int* __restrict__ aux, int n) {
  __shared__ int s[256];
  int t = threadIdx.x, i = blockIdx.x*256 + t;
  int v = (i < n) ? in[i] : 0;
  s[t] = v; __syncthreads();
  for (int off = 1; off < 256; off <<= 1) {
    int x = (t >= off) ? s[t - off] : 0;
    __syncthreads();
    s[t] += x;
    __syncthreads();
  }
  if (i < n) out[i] = s[t] - v;
  if (t == 255) aux[blockIdx.x] = s[255];
}
__global__ __launch_bounds__(1024) void k_scan2(int* __restrict__ aux, int nb) {
  __shared__ int s[1024];
  int t = threadIdx.x;
  int v = (t < nb) ? aux[t] : 0;
  s[t] = v; __syncthreads();
  for (int off = 1; off < 1024; off <<= 1) {
    int x = (t >= off) ? s[t-off] : 0;
    __syncthreads();
    s[t] += x;
    __syncthreads();
  }
  if (t < nb) aux[t] = s[t] - v;
}
__global__ __launch_bounds__(256) void k_scan3(int* __restrict__ out, const int* __restrict__ aux,
                                               int n, int total) {
  int i = blockIdx.x*256 + threadIdx.x;
  if (i < n) out[i] += aux[blockIdx.x];
  if (i == 0) out[n] = total;
}
__global__ void k_scatter(const int* __restrict__ sc, const int* __restrict__ dc,
                          const int* __restrict__ sv, const int* __restrict__ dv,
                          const int* __restrict__ off_c, int* __restrict__ cur_c, int* __restrict__ lst_c,
                          const int* __restrict__ off_v, int* __restrict__ cur_v, int* __restrict__ lst_v) {
  for (int e = blockIdx.x*blockDim.x + threadIdx.x; e < NE; e += gridDim.x*blockDim.x) {
    int d = dc[e]; int p = atomicAdd(&cur_c[d], 1); lst_c[off_c[d] + p] = sc[e];
    d = dv[e];     p = atomicAdd(&cur_v[d], 1);     lst_v[off_v[d] + p] = sv[e];
  }
}

// ---------------- gather (f32) ----------------
__global__ __launch_bounds__(256) void k_gather(const float* __restrict__ tab,
    const int* __restrict__ off, const int* __restrict__ lst,
    float* __restrict__ out, int n) {
  int wid = (blockIdx.x * 256 + threadIdx.x) >> 6;
  int lane = threadIdx.x & 63;
  if (wid >= n) return;
  int s0 = off[wid], s1 = off[wid+1];
  float a0 = 0.f, a1 = 0.f;
  for (int p = s0; p < s1; ++p) {
    int src = lst[p];
    const float* row = tab + (size_t)src * H;
    a0 += row[lane]; a1 += row[lane+64];
  }
  float inv = 1.0f / ((float)(s1 - s0) + 1e-6f);
  out[(size_t)wid*H + lane]      = a0 * inv;
  out[(size_t)wid*H + lane + 64] = a1 * inv;
}

// ---------------- SIMT row matmul (r1-proven), used for gates ----------------
template <int ACC>
__global__ __launch_bounds__(256) void k_matmul(const float* __restrict__ IN,
    const float* __restrict__ Wg, float* __restrict__ OUT, int n) {
  __shared__ unsigned short Wl[H*H];
  __shared__ float rowbuf[4][2][H];
  const int tid = threadIdx.x, wv = tid >> 6, lane = tid & 63;
  for (int i = tid; i < H*H; i += 256) {
    unsigned int u = __float_as_uint(Wg[i]);
    Wl[i] = (unsigned short)((u + 0x7FFFu + ((u >> 16) & 1u)) >> 16);
  }
  __syncthreads();
  const int base = blockIdx.x * 64 + wv * 16;
  for (int rr = 0; rr < 16; rr += 2) {
    int r0 = base + rr, r1 = r0 + 1;
    if (r0 < n) ((float2*)rowbuf[wv][0])[lane] = ((const float2*)(IN + (size_t)r0*H))[lane];
    if (r1 < n) ((float2*)rowbuf[wv][1])[lane] = ((const float2*)(IN + (size_t)r1*H))[lane];
    __syncthreads();
    float acc00 = 0.f, acc01 = 0.f, acc10 = 0.f, acc11 = 0.f;
    const uint32_t* Wp = (const uint32_t*)Wl;
    const float2* rb0 = (const float2*)rowbuf[wv][0];
    const float2* rb1 = (const float2*)rowbuf[wv][1];
#pragma unroll 8
    for (int k = 0; k < H; k += 2) {
      float2 a0 = rb0[k >> 1];
      float2 a1 = rb1[k >> 1];
      uint32_t wp0 = Wp[k*64 + lane];
      uint32_t wp1 = Wp[(k+1)*64 + lane];
      float w00 = __uint_as_float(wp0 << 16);
      float w01 = __uint_as_float(wp0 & 0xFFFF0000u);
      float w10 = __uint_as_float(wp1 << 16);
      float w11 = __uint_as_float(wp1 & 0xFFFF0000u);
      acc00 = fmaf(a0.x, w00, acc00); acc01 = fmaf(a0.x, w01, acc01);
      acc10 = fmaf(a1.x, w00, acc10); acc11 = fmaf(a1.x, w01, acc11);
      acc00 = fmaf(a0.y, w10, acc00); acc01 = fmaf(a0.y, w11, acc01);
      acc10 = fmaf(a1.y, w10, acc10); acc11 = fmaf(a1.y, w11, acc11);
    }
    __syncthreads();
    if (r0 < n) {
      float2* o = (float2*)(OUT + (size_t)r0*H + 2*lane);
      if (ACC) { float2 pv = *o; pv.x += acc00; pv.y += acc01; *o = pv; }
      else *o = make_float2(acc00, acc01);
    }
    if (r1 < n) {
      float2* o = (float2*)(OUT + (size_t)r1*H + 2*lane);
      if (ACC) { float2 pv = *o; pv.x += acc10; pv.y += acc11; *o = pv; }
      else *o = make_float2(acc10, acc11);
    }
  }
}

// ---------------- PURE MFMA matmul: OUT = A @ W (split-operand), no epilogue ----------------
__global__ __launch_bounds__(256) void k_mm(const float* __restrict__ A,
    const unsigned short* __restrict__ Wph, const unsigned short* __restrict__ Wpl,
    float* __restrict__ OUT, int n) {
  const int wv = threadIdx.x >> 6, lane = threadIdx.x & 63;
  const int rbase = blockIdx.x*64 + wv*16;
  if (rbase >= n) return;
  const int g = lane >> 4, c15 = lane & 15;
  int arow = rbase + c15; if (arow > n-1) arow = n-1;
  const float* Ar = A + (size_t)arow*H + g*8;
  bf16x8 ahi[4], alo[4];
#pragma unroll
  for (int kb = 0; kb < 4; ++kb) {
    float4 p0 = *(const float4*)(Ar + kb*32);
    float4 p1 = *(const float4*)(Ar + kb*32 + 4);
    bf16x8 h, l;
    short2 s;
    s = splitbf(p0.x); h[0] = s.x; l[0] = s.y;
    s = splitbf(p0.y); h[1] = s.x; l[1] = s.y;
    s = splitbf(p0.z); h[2] = s.x; l[2] = s.y;
    s = splitbf(p0.w); h[3] = s.x; l[3] = s.y;
    s = splitbf(p1.x); h[4] = s.x; l[4] = s.y;
    s = splitbf(p1.y); h[5] = s.x; l[5] = s.y;
    s = splitbf(p1.z); h[6] = s.x; l[6] = s.y;
    s = splitbf(p1.w); h[7] = s.x; l[7] = s.y;
    ahi[kb] = h; alo[kb] = l;
  }
  const bf16x8* Bph = (const bf16x8*)Wph;
  const bf16x8* Bpl = (const bf16x8*)Wpl;
  f32x4 zero = {0.f, 0.f, 0.f, 0.f};
  f32x4 acc[8];
#pragma unroll
  for (int ct = 0; ct < 8; ++ct) acc[ct] = zero;
#pragma unroll
  for (int kb = 0; kb < 4; ++kb)
#pragma unroll
    for (int ct = 0; ct < 8; ++ct) {
      bf16x8 bh = Bph[(kb*8+ct)*64 + lane];
      bf16x8 bl = Bpl[(kb*8+ct)*64 + lane];
      acc[ct] = __builtin_amdgcn_mfma_f32_16x16x32_bf16(ahi[kb], bh, acc[ct], 0, 0, 0);
      acc[ct] = __builtin_amdgcn_mfma_f32_16x16x32_bf16(alo[kb], bh, acc[ct], 0, 0, 0);
      acc[ct] = __builtin_amdgcn_mfma_f32_16x16x32_bf16(ahi[kb], bl, acc[ct], 0, 0, 0);
    }
  // write per assumed C/D map: row = rbase + g*4 + r, col = ct*16 + c15
#pragma unroll
  for (int r = 0; r < 4; ++r) {
    int rg = rbase + g*4 + r;
    if (rg >= n) continue;
    float* op = OUT + (size_t)rg*H + c15;
#pragma unroll
    for (int ct = 0; ct < 8; ++ct) op[ct*16] = acc[ct][r];
  }
}

// ---------------- con epilogue (r1-proven SIMT) ----------------
__global__ __launch_bounds__(256) void k_con_epi(const float* __restrict__ t,
    const int* __restrict__ cnt, const float* __restrict__ xc,
    const float* __restrict__ bfu, const float* __restrict__ wu, const float* __restrict__ bu,
    const float* __restrict__ g, const float* __restrict__ bb, float* __restrict__ out) {
  int wid = (blockIdx.x*256 + threadIdx.x) >> 6, lane = threadIdx.x & 63;
  if (wid >= NCN) return;
  float cf = (float)cnt[wid];
  float scale = cf / (cf + 1e-6f);
  float clue = xc[wid];
  int c0 = lane, c1 = lane + 64;
  float v0 = t[(size_t)wid*H+c0] + scale*bfu[c0] + clue*wu[H*H + c0] + bu[c0];
  float v1 = t[(size_t)wid*H+c1] + scale*bfu[c1] + clue*wu[H*H + c1] + bu[c1];
  v0 = fmaxf(v0, 0.f); v1 = fmaxf(v1, 0.f);
  float mu = wredsum(v0 + v1) * (1.0f/H);
  float d0 = v0 - mu, d1 = v1 - mu;
  float var = wredsum(d0*d0 + d1*d1) * (1.0f/H);
  float r = rsqrtf(var + 1e-5f);
  out[(size_t)wid*H + c0] = d0*r*g[c0] + bb[c0];
  out[(size_t)wid*H + c1] = d1*r*g[c1] + bb[c1];
}

// ---------------- var epilogue (r1-proven SIMT) ----------------
__global__ __launch_bounds__(256) void k_var_epi(const float* __restrict__ t,
    const int* __restrict__ cnt, const float* __restrict__ bc,
    const float* __restrict__ g, const float* __restrict__ bb, float* __restrict__ out) {
  int wid = (blockIdx.x*256 + threadIdx.x) >> 6, lane = threadIdx.x & 63;
  if (wid >= NVN) return;
  float cf = (float)cnt[wid];
  float scale = cf / (cf + 1e-6f);
  int c0 = lane, c1 = lane + 64;
  float v0 = fmaxf(t[(size_t)wid*H+c0] + scale*bc[c0], 0.f);
  float v1 = fmaxf(t[(size_t)wid*H+c1] + scale*bc[c1], 0.f);
  float mu = wredsum(v0 + v1) * (1.0f/H);
  float d0 = v0 - mu, d1 = v1 - mu;
  float var = wredsum(d0*d0 + d1*d1) * (1.0f/H);
  float r = rsqrtf(var + 1e-5f);
  out[(size_t)wid*H + c0] = d0*r*g[c0] + bb[c0];
  out[(size_t)wid*H + c1] = d1*r*g[c1] + bb[c1];
}

// ---------------- gate (r1-proven) ----------------
__global__ __launch_bounds__(256) void k_gate(const float* __restrict__ t, const float* __restrict__ nw,
    float* __restrict__ hcur, const float* __restrict__ gb, int n4) {
  int i = blockIdx.x*256 + threadIdx.x;
  if (i >= n4) return;
  float4 tv = ((const float4*)t)[i];
  float4 nv = ((const float4*)nw)[i];
  float4 hv = ((const float4*)hcur)[i];
  float4 gv = ((const float4*)gb)[i & 31];
  float g0 = sigmoidf(tv.x + gv.x), g1 = sigmoidf(tv.y + gv.y);
  float g2 = sigmoidf(tv.z + gv.z), g3 = sigmoidf(tv.w + gv.w);
  float4 o;
  o.x = g0*nv.x + (1.f-g0)*hv.x;
  o.y = g1*nv.y + (1.f-g1)*hv.y;
  o.z = g2*nv.z + (1.f-g2)*hv.z;
  o.w = g3*nv.w + (1.f-g3)*hv.w;
  ((float4*)hcur)[i] = o;
}

extern "C" void kernel_launch(void* const* d_in, const int* in_sizes, int n_in,
                              void* d_out, int out_size, void* d_ws, size_t ws_size,
                              hipStream_t stream) {
  const float* x_var   = (const float*)d_in[0];
  const float* x_con   = (const float*)d_in[1];
  const int*   evc_src = (const int*)d_in[2];
  const int*   evc_dst = (const int*)d_in[3];
  const int*   ecv_src = (const int*)d_in[4];
  const int*   ecv_dst = (const int*)d_in[5];
  const float* vproj_w = (const float*)d_in[6];
  const float* vproj_b = (const float*)d_in[7];
  const float* cproj_w = (const float*)d_in[8];
  const float* cproj_b = (const float*)d_in[9];
  const float* wmsg    = (const float*)d_in[10];
  const float* bmsg    = (const float*)d_in[11];
  const float* wupd    = (const float*)d_in[12];
  const float* bupd    = (const float*)d_in[13];
  const float* v2c_ln_g = (const float*)d_in[14];
  const float* v2c_ln_b = (const float*)d_in[15];
  const float* wc2v    = (const float*)d_in[16];
  const float* bc2v    = (const float*)d_in[17];
  const float* c2v_ln_g = (const float*)d_in[18];
  const float* c2v_ln_b = (const float*)d_in[19];
  const float* vgate_w = (const float*)d_in[20];
  const float* vgate_b = (const float*)d_in[21];
  const float* cgate_w = (const float*)d_in[22];
  const float* cgate_b = (const float*)d_in[23];
  const float* var_ln_g = (const float*)d_in[24];
  const float* var_ln_b = (const float*)d_in[25];
  const float* con_ln_g = (const float*)d_in[26];
  const float* con_ln_b = (const float*)d_in[27];
  float* hv = (float*)d_out;

  char* p = (char*)d_ws;
  auto carve = [&](size_t bytes) { char* r = p; p += (bytes + 255) & ~(size_t)255; return r; };
  int* cnt_c = (int*)carve((size_t)NCN*4);
  int* cur_c = (int*)carve((size_t)NCN*4);
  int* cnt_v = (int*)carve((size_t)NVN*4);
  int* cur_v = (int*)carve((size_t)NVN*4);
  int* off_c = (int*)carve((size_t)(NCN+1)*4);
  int* off_v = (int*)carve((size_t)(NVN+1)*4);
  int* aux   = (int*)carve(1024*4);
  int* lst_c = (int*)carve((size_t)NE*4);
  int* lst_v = (int*)carve((size_t)NE*4);
  float* wf  = (float*)carve((size_t)H*H*4);
  float* bfu = (float*)carve((size_t)H*4);
  unsigned short* wfph = (unsigned short*)carve((size_t)H*H*2);
  unsigned short* wfpl = (unsigned short*)carve((size_t)H*H*2);
  unsigned short* wvph = (unsigned short*)carve((size_t)H*H*2);
  unsigned short* wvpl = (unsigned short*)carve((size_t)H*H*2);
  float* hc    = (float*)carve((size_t)NCN*H*4);
  float* c_new = (float*)carve((size_t)NCN*H*4);
  float* v_new = (float*)carve((size_t)NVN*H*4);
  float* t_c   = (float*)carve((size_t)NCN*H*4);
  float* t_v   = (float*)carve((size_t)NVN*H*4);
  if ((size_t)(p - (char*)d_ws) > ws_size) return;

  (void)hipMemsetAsync(cnt_c, 0, (size_t)NCN*4, stream);
  (void)hipMemsetAsync(cur_c, 0, (size_t)NCN*4, stream);
  (void)hipMemsetAsync(cnt_v, 0, (size_t)NVN*4, stream);
  (void)hipMemsetAsync(cur_v, 0, (size_t)NVN*4, stream);

  k_fuse_w<<<64, 256, 0, stream>>>(wmsg, wupd, wf);
  k_fuse_b<<<1, 128, 0, stream>>>(bmsg, wupd, bfu);
  k_perm2<<<(H*H+255)/256, 256, 0, stream>>>(wf, wfph, wfpl, H);
  k_perm2<<<(H*H+255)/256, 256, 0, stream>>>(wc2v, wvph, wvpl, H);

  k_count<<<1024, 256, 0, stream>>>(evc_dst, ecv_dst, cnt_c, cnt_v);
  int nbc = (NCN + 255)/256, nbv = (NVN + 255)/256;
  k_scan1<<<nbc, 256, 0, stream>>>(cnt_c, off_c, aux, NCN);
  k_scan2<<<1, 1024, 0, stream>>>(aux, nbc);
  k_scan3<<<nbc, 256, 0, stream>>>(off_c, aux, NCN, NE);
  k_scan1<<<nbv, 256, 0, stream>>>(cnt_v, off_v, aux, NVN);
  k_scan2<<<1, 1024, 0, stream>>>(aux, nbv);
  k_scan3<<<nbv, 256, 0, stream>>>(off_v, aux, NVN, NE);
  k_scatter<<<1024, 256, 0, stream>>>(evc_src, evc_dst, ecv_src, ecv_dst,
                                      off_c, cur_c, lst_c, off_v, cur_v, lst_v);

  k_init_var<<<NVN/4, 256, 0, stream>>>(x_var, vproj_w, vproj_b, var_ln_g, var_ln_b, hv);
  k_init_con<<<NCN/4, 256, 0, stream>>>(x_con, cproj_w, cproj_b, con_ln_g, con_ln_b, hc);

  for (int r = 0; r < 2; ++r) {
    // ---- v2c ----
    k_gather<<<(NCN+3)/4, 256, 0, stream>>>(hv, off_c, lst_c, t_c, NCN);
    k_mm<<<(NCN+63)/64, 256, 0, stream>>>(t_c, wfph, wfpl, t_c, NCN);   // pure MFMA matmul (in-place, wave-local rows)
    k_con_epi<<<(NCN+3)/4, 256, 0, stream>>>(t_c, cnt_c, x_con, bfu, wupd, bupd,
                                             v2c_ln_g, v2c_ln_b, c_new);
    k_matmul<0><<<(NCN+63)/64, 256, 0, stream>>>(hc, cgate_w, t_c, NCN);
    k_matmul<1><<<(NCN+63)/64, 256, 0, stream>>>(c_new, cgate_w + H*H, t_c, NCN);
    k_gate<<<(NCN*H/4 + 255)/256, 256, 0, stream>>>(t_c, c_new, hc, cgate_b, NCN*H/4);
    // ---- c2v ----
    k_gather<<<(NVN+3)/4, 256, 0, stream>>>(hc, off_v, lst_v, t_v, NVN);
    k_mm<<<(NVN+63)/64, 256, 0, stream>>>(t_v, wvph, wvpl, t_v, NVN);   // pure MFMA matmul
    k_var_epi<<<(NVN+3)/4, 256, 0, stream>>>(t_v, cnt_v, bc2v, c2v_ln_g, c2v_ln_b, v_new);
    k_matmul<0><<<(NVN+63)/64, 256, 0, stream>>>(hv, vgate_w, t_v, NVN);
    k_matmul<1><<<(NVN+63)/64, 256, 0, stream>>>(v_new, vgate_w + H*H, t_v, NVN);
    k_gate<<<(NVN*H/4 + 255)/256, 256, 0, stream>>>(t_v, v_new, hv, vgate_b, NVN*H/4);
  }
}

// Round 8
// 950.213 us; speedup vs baseline: 1.5692x; 1.3943x over previous
//
#include <hip/hip_runtime.h>
#include <stdint.h>

#define NVN 100000
#define NCN 50000
#define NE  800000
#define H   128

typedef __attribute__((ext_vector_type(8))) short bf16x8;
typedef __attribute__((ext_vector_type(4))) float f32x4;

static __device__ __forceinline__ float wredsum(float v) {
#pragma unroll
  for (int off = 32; off > 0; off >>= 1) v += __shfl_xor(v, off, 64);
  return v;
}
static __device__ __forceinline__ float sigmoidf(float x) { return 1.0f / (1.0f + __expf(-x)); }
static __device__ __forceinline__ unsigned short f2bf(float f) {
  unsigned int u = __float_as_uint(f);
  return (unsigned short)((u + 0x7FFFu + ((u >> 16) & 1u)) >> 16);  // RNE
}
static __device__ __forceinline__ short2 splitbf(float f) {
  unsigned short h = f2bf(f);
  float hf = __uint_as_float(((unsigned int)h) << 16);
  short2 r;
  r.x = (short)h;
  r.y = (short)f2bf(f - hf);
  return r;
}

// ---------------- init: h = LN(relu(x @ W + b)) ----------------
__global__ __launch_bounds__(256) void k_init_var(const float* __restrict__ xv,
    const float* __restrict__ w, const float* __restrict__ b,
    const float* __restrict__ g, const float* __restrict__ bb, float* __restrict__ hv) {
  int wid = (blockIdx.x * 256 + threadIdx.x) >> 6;
  int lane = threadIdx.x & 63;
  if (wid >= NVN) return;
  float x0 = xv[wid*4+0], x1 = xv[wid*4+1], x2 = xv[wid*4+2], x3 = xv[wid*4+3];
  int c0 = lane, c1 = lane + 64;
  float v0 = b[c0] + x0*w[c0] + x1*w[H+c0] + x2*w[2*H+c0] + x3*w[3*H+c0];
  float v1 = b[c1] + x0*w[c1] + x1*w[H+c1] + x2*w[2*H+c1] + x3*w[3*H+c1];
  v0 = fmaxf(v0, 0.f); v1 = fmaxf(v1, 0.f);
  float mu = wredsum(v0 + v1) * (1.0f/H);
  float d0 = v0 - mu, d1 = v1 - mu;
  float var = wredsum(d0*d0 + d1*d1) * (1.0f/H);
  float r = rsqrtf(var + 1e-5f);
  hv[(size_t)wid*H + c0] = d0*r*g[c0] + bb[c0];
  hv[(size_t)wid*H + c1] = d1*r*g[c1] + bb[c1];
}

__global__ __launch_bounds__(256) void k_init_con(const float* __restrict__ xc,
    const float* __restrict__ w, const float* __restrict__ b,
    const float* __restrict__ g, const float* __restrict__ bb, float* __restrict__ hc) {
  int wid = (blockIdx.x * 256 + threadIdx.x) >> 6;
  int lane = threadIdx.x & 63;
  if (wid >= NCN) return;
  float x = xc[wid];
  int c0 = lane, c1 = lane + 64;
  float v0 = fmaxf(b[c0] + x*w[c0], 0.f);
  float v1 = fmaxf(b[c1] + x*w[c1], 0.f);
  float mu = wredsum(v0 + v1) * (1.0f/H);
  float d0 = v0 - mu, d1 = v1 - mu;
  float var = wredsum(d0*d0 + d1*d1) * (1.0f/H);
  float r = rsqrtf(var + 1e-5f);
  hc[(size_t)wid*H + c0] = d0*r*g[c0] + bb[c0];
  hc[(size_t)wid*H + c1] = d1*r*g[c1] + bb[c1];
}

// ---------------- weight fusion ----------------
__global__ void k_fuse_w(const float* __restrict__ wm, const float* __restrict__ wu,
                         float* __restrict__ wf) {
  int idx = blockIdx.x*256 + threadIdx.x;   // 16384
  int i = idx >> 7, j = idx & 127;
  float a = 0.f;
  for (int k = 0; k < H; ++k) a = fmaf(wm[i*H+k], wu[k*H+j], a);
  wf[idx] = a;
}
__global__ void k_fuse_b(const float* __restrict__ bm, const float* __restrict__ wu,
                         float* __restrict__ bf) {
  int j = threadIdx.x;
  float a = 0.f;
  for (int k = 0; k < H; ++k) a = fmaf(bm[k], wu[k*H+j], a);
  bf[j] = a;
}

// ---------------- weight permutation into MFMA B-fragment order, hi+lo split ----------------
__global__ __launch_bounds__(256) void k_perm2(const float* __restrict__ W,
    unsigned short* __restrict__ Whi, unsigned short* __restrict__ Wlo, int K) {
  int idx = blockIdx.x*256 + threadIdx.x;
  if (idx >= K*H) return;
  int j = idx & 7, lane = (idx >> 3) & 63, ct = (idx >> 9) & 7, kb = idx >> 12;
  int k = kb*32 + (lane >> 4)*8 + j, c = ct*16 + (lane & 15);
  float w = W[k*H + c];
  unsigned short h = f2bf(w);
  float hf = __uint_as_float(((unsigned int)h) << 16);
  Whi[idx] = h;
  Wlo[idx] = f2bf(w - hf);
}

// ---------------- CSR build ----------------
__global__ void k_count(const int* __restrict__ dc, const int* __restrict__ dv,
                        int* __restrict__ cnt_c, int* __restrict__ cnt_v) {
  for (int e = blockIdx.x*blockDim.x + threadIdx.x; e < NE; e += gridDim.x*blockDim.x) {
    atomicAdd(&cnt_c[dc[e]], 1);
    atomicAdd(&cnt_v[dv[e]], 1);
  }
}
__global__ __launch_bounds__(256) void k_scan1(const int* __restrict__ in, int* __restrict__ out,
                                               int* __restrict__ aux, int n) {
  __shared__ int s[256];
  int t = threadIdx.x, i = blockIdx.x*256 + t;
  int v = (i < n) ? in[i] : 0;
  s[t] = v; __syncthreads();
  for (int off = 1; off < 256; off <<= 1) {
    int x = (t >= off) ? s[t - off] : 0;
    __syncthreads();
    s[t] += x;
    __syncthreads();
  }
  if (i < n) out[i] = s[t] - v;
  if (t == 255) aux[blockIdx.x] = s[255];
}
__global__ __launch_bounds__(1024) void k_scan2(int* __restrict__ aux, int nb) {
  __shared__ int s[1024];
  int t = threadIdx.x;
  int v = (t < nb) ? aux[t] : 0;
  s[t] = v; __syncthreads();
  for (int off = 1; off < 1024; off <<= 1) {
    int x = (t >= off) ? s[t-off] : 0;
    __syncthreads();
    s[t] += x;
    __syncthreads();
  }
  if (t < nb) aux[t] = s[t] - v;
}
__global__ __launch_bounds__(256) void k_scan3(int* __restrict__ out, const int* __restrict__ aux,
                                               int n, int total) {
  int i = blockIdx.x*256 + threadIdx.x;
  if (i < n) out[i] += aux[blockIdx.x];
  if (i == 0) out[n] = total;
}
__global__ void k_scatter(const int* __restrict__ sc, const int* __restrict__ dc,
                          const int* __restrict__ sv, const int* __restrict__ dv,
                          const int* __restrict__ off_c, int* __restrict__ cur_c, int* __restrict__ lst_c,
                          const int* __restrict__ off_v, int* __restrict__ cur_v, int* __restrict__ lst_v) {
  for (int e = blockIdx.x*blockDim.x + threadIdx.x; e < NE; e += gridDim.x*blockDim.x) {
    int d = dc[e]; int p = atomicAdd(&cur_c[d], 1); lst_c[off_c[d] + p] = sc[e];
    d = dv[e];     p = atomicAdd(&cur_v[d], 1);     lst_v[off_v[d] + p] = sv[e];
  }
}

// ---------------- gather (f32) ----------------
__global__ __launch_bounds__(256) void k_gather(const float* __restrict__ tab,
    const int* __restrict__ off, const int* __restrict__ lst,
    float* __restrict__ out, int n) {
  int wid = (blockIdx.x * 256 + threadIdx.x) >> 6;
  int lane = threadIdx.x & 63;
  if (wid >= n) return;
  int s0 = off[wid], s1 = off[wid+1];
  float a0 = 0.f, a1 = 0.f;
  for (int p = s0; p < s1; ++p) {
    int src = lst[p];
    const float* row = tab + (size_t)src * H;
    a0 += row[lane]; a1 += row[lane+64];
  }
  float inv = 1.0f / ((float)(s1 - s0) + 1e-6f);
  out[(size_t)wid*H + lane]      = a0 * inv;
  out[(size_t)wid*H + lane + 64] = a1 * inv;
}

// ---------------- PURE MFMA matmul: OUT = A @ W (split-operand), no epilogue ----------------
__global__ __launch_bounds__(256) void k_mm(const float* __restrict__ A,
    const unsigned short* __restrict__ Wph, const unsigned short* __restrict__ Wpl,
    float* __restrict__ OUT, int n) {
  const int wv = threadIdx.x >> 6, lane = threadIdx.x & 63;
  const int rbase = blockIdx.x*64 + wv*16;
  if (rbase >= n) return;
  const int g = lane >> 4, c15 = lane & 15;
  int arow = rbase + c15; if (arow > n-1) arow = n-1;
  const float* Ar = A + (size_t)arow*H + g*8;
  bf16x8 ahi[4], alo[4];
#pragma unroll
  for (int kb = 0; kb < 4; ++kb) {
    float4 p0 = *(const float4*)(Ar + kb*32);
    float4 p1 = *(const float4*)(Ar + kb*32 + 4);
    bf16x8 h, l;
    short2 s;
    s = splitbf(p0.x); h[0] = s.x; l[0] = s.y;
    s = splitbf(p0.y); h[1] = s.x; l[1] = s.y;
    s = splitbf(p0.z); h[2] = s.x; l[2] = s.y;
    s = splitbf(p0.w); h[3] = s.x; l[3] = s.y;
    s = splitbf(p1.x); h[4] = s.x; l[4] = s.y;
    s = splitbf(p1.y); h[5] = s.x; l[5] = s.y;
    s = splitbf(p1.z); h[6] = s.x; l[6] = s.y;
    s = splitbf(p1.w); h[7] = s.x; l[7] = s.y;
    ahi[kb] = h; alo[kb] = l;
  }
  const bf16x8* Bph = (const bf16x8*)Wph;
  const bf16x8* Bpl = (const bf16x8*)Wpl;
  f32x4 zero = {0.f, 0.f, 0.f, 0.f};
  f32x4 acc[8];
#pragma unroll
  for (int ct = 0; ct < 8; ++ct) acc[ct] = zero;
#pragma unroll
  for (int kb = 0; kb < 4; ++kb)
#pragma unroll
    for (int ct = 0; ct < 8; ++ct) {
      bf16x8 bh = Bph[(kb*8+ct)*64 + lane];
      bf16x8 bl = Bpl[(kb*8+ct)*64 + lane];
      acc[ct] = __builtin_amdgcn_mfma_f32_16x16x32_bf16(ahi[kb], bh, acc[ct], 0, 0, 0);
      acc[ct] = __builtin_amdgcn_mfma_f32_16x16x32_bf16(alo[kb], bh, acc[ct], 0, 0, 0);
      acc[ct] = __builtin_amdgcn_mfma_f32_16x16x32_bf16(ahi[kb], bl, acc[ct], 0, 0, 0);
    }
#pragma unroll
  for (int r = 0; r < 4; ++r) {
    int rg = rbase + g*4 + r;
    if (rg >= n) continue;
    float* op = OUT + (size_t)rg*H + c15;
#pragma unroll
    for (int ct = 0; ct < 8; ++ct) op[ct*16] = acc[ct][r];
  }
}

// ---------------- PURE MFMA concat-matmul: OUT = A1 @ W[:H] + A2 @ W[H:] (K=256) ----------------
__global__ __launch_bounds__(256) void k_mm2(const float* __restrict__ A1,
    const float* __restrict__ A2,
    const unsigned short* __restrict__ Wph, const unsigned short* __restrict__ Wpl,
    float* __restrict__ OUT, int n) {
  const int wv = threadIdx.x >> 6, lane = threadIdx.x & 63;
  const int rbase = blockIdx.x*64 + wv*16;
  if (rbase >= n) return;
  const int g = lane >> 4, c15 = lane & 15;
  int arow = rbase + c15; if (arow > n-1) arow = n-1;
  const float* Ar1 = A1 + (size_t)arow*H + g*8;
  const float* Ar2 = A2 + (size_t)arow*H + g*8;
  bf16x8 ahi[8], alo[8];
#pragma unroll
  for (int kb = 0; kb < 8; ++kb) {
    const float* src = (kb < 4) ? (Ar1 + kb*32) : (Ar2 + (kb-4)*32);
    float4 p0 = *(const float4*)(src);
    float4 p1 = *(const float4*)(src + 4);
    bf16x8 h, l;
    short2 s;
    s = splitbf(p0.x); h[0] = s.x; l[0] = s.y;
    s = splitbf(p0.y); h[1] = s.x; l[1] = s.y;
    s = splitbf(p0.z); h[2] = s.x; l[2] = s.y;
    s = splitbf(p0.w); h[3] = s.x; l[3] = s.y;
    s = splitbf(p1.x); h[4] = s.x; l[4] = s.y;
    s = splitbf(p1.y); h[5] = s.x; l[5] = s.y;
    s = splitbf(p1.z); h[6] = s.x; l[6] = s.y;
    s = splitbf(p1.w); h[7] = s.x; l[7] = s.y;
    ahi[kb] = h; alo[kb] = l;
  }
  const bf16x8* Bph = (const bf16x8*)Wph;
  const bf16x8* Bpl = (const bf16x8*)Wpl;
  f32x4 zero = {0.f, 0.f, 0.f, 0.f};
  f32x4 acc[8];
#pragma unroll
  for (int ct = 0; ct < 8; ++ct) acc[ct] = zero;
#pragma unroll
  for (int kb = 0; kb < 8; ++kb)
#pragma unroll
    for (int ct = 0; ct < 8; ++ct) {
      bf16x8 bh = Bph[(kb*8+ct)*64 + lane];
      bf16x8 bl = Bpl[(kb*8+ct)*64 + lane];
      acc[ct] = __builtin_amdgcn_mfma_f32_16x16x32_bf16(ahi[kb], bh, acc[ct], 0, 0, 0);
      acc[ct] = __builtin_amdgcn_mfma_f32_16x16x32_bf16(alo[kb], bh, acc[ct], 0, 0, 0);
      acc[ct] = __builtin_amdgcn_mfma_f32_16x16x32_bf16(ahi[kb], bl, acc[ct], 0, 0, 0);
    }
#pragma unroll
  for (int r = 0; r < 4; ++r) {
    int rg = rbase + g*4 + r;
    if (rg >= n) continue;
    float* op = OUT + (size_t)rg*H + c15;
#pragma unroll
    for (int ct = 0; ct < 8; ++ct) op[ct*16] = acc[ct][r];
  }
}

// ---------------- con epilogue (r1-proven SIMT) ----------------
__global__ __launch_bounds__(256) void k_con_epi(const float* __restrict__ t,
    const int* __restrict__ cnt, const float* __restrict__ xc,
    const float* __restrict__ bfu, const float* __restrict__ wu, const float* __restrict__ bu,
    const float* __restrict__ g, const float* __restrict__ bb, float* __restrict__ out) {
  int wid = (blockIdx.x*256 + threadIdx.x) >> 6, lane = threadIdx.x & 63;
  if (wid >= NCN) return;
  float cf = (float)cnt[wid];
  float scale = cf / (cf + 1e-6f);
  float clue = xc[wid];
  int c0 = lane, c1 = lane + 64;
  float v0 = t[(size_t)wid*H+c0] + scale*bfu[c0] + clue*wu[H*H + c0] + bu[c0];
  float v1 = t[(size_t)wid*H+c1] + scale*bfu[c1] + clue*wu[H*H + c1] + bu[c1];
  v0 = fmaxf(v0, 0.f); v1 = fmaxf(v1, 0.f);
  float mu = wredsum(v0 + v1) * (1.0f/H);
  float d0 = v0 - mu, d1 = v1 - mu;
  float var = wredsum(d0*d0 + d1*d1) * (1.0f/H);
  float r = rsqrtf(var + 1e-5f);
  out[(size_t)wid*H + c0] = d0*r*g[c0] + bb[c0];
  out[(size_t)wid*H + c1] = d1*r*g[c1] + bb[c1];
}

// ---------------- var epilogue (r1-proven SIMT) ----------------
__global__ __launch_bounds__(256) void k_var_epi(const float* __restrict__ t,
    const int* __restrict__ cnt, const float* __restrict__ bc,
    const float* __restrict__ g, const float* __restrict__ bb, float* __restrict__ out) {
  int wid = (blockIdx.x*256 + threadIdx.x) >> 6, lane = threadIdx.x & 63;
  if (wid >= NVN) return;
  float cf = (float)cnt[wid];
  float scale = cf / (cf + 1e-6f);
  int c0 = lane, c1 = lane + 64;
  float v0 = fmaxf(t[(size_t)wid*H+c0] + scale*bc[c0], 0.f);
  float v1 = fmaxf(t[(size_t)wid*H+c1] + scale*bc[c1], 0.f);
  float mu = wredsum(v0 + v1) * (1.0f/H);
  float d0 = v0 - mu, d1 = v1 - mu;
  float var = wredsum(d0*d0 + d1*d1) * (1.0f/H);
  float r = rsqrtf(var + 1e-5f);
  out[(size_t)wid*H + c0] = d0*r*g[c0] + bb[c0];
  out[(size_t)wid*H + c1] = d1*r*g[c1] + bb[c1];
}

// ---------------- gate (r1-proven) ----------------
__global__ __launch_bounds__(256) void k_gate(const float* __restrict__ t, const float* __restrict__ nw,
    float* __restrict__ hcur, const float* __restrict__ gb, int n4) {
  int i = blockIdx.x*256 + threadIdx.x;
  if (i >= n4) return;
  float4 tv = ((const float4*)t)[i];
  float4 nv = ((const float4*)nw)[i];
  float4 hv = ((const float4*)hcur)[i];
  float4 gv = ((const float4*)gb)[i & 31];
  float g0 = sigmoidf(tv.x + gv.x), g1 = sigmoidf(tv.y + gv.y);
  float g2 = sigmoidf(tv.z + gv.z), g3 = sigmoidf(tv.w + gv.w);
  float4 o;
  o.x = g0*nv.x + (1.f-g0)*hv.x;
  o.y = g1*nv.y + (1.f-g1)*hv.y;
  o.z = g2*nv.z + (1.f-g2)*hv.z;
  o.w = g3*nv.w + (1.f-g3)*hv.w;
  ((float4*)hcur)[i] = o;
}

extern "C" void kernel_launch(void* const* d_in, const int* in_sizes, int n_in,
                              void* d_out, int out_size, void* d_ws, size_t ws_size,
                              hipStream_t stream) {
  const float* x_var   = (const float*)d_in[0];
  const float* x_con   = (const float*)d_in[1];
  const int*   evc_src = (const int*)d_in[2];
  const int*   evc_dst = (const int*)d_in[3];
  const int*   ecv_src = (const int*)d_in[4];
  const int*   ecv_dst = (const int*)d_in[5];
  const float* vproj_w = (const float*)d_in[6];
  const float* vproj_b = (const float*)d_in[7];
  const float* cproj_w = (const float*)d_in[8];
  const float* cproj_b = (const float*)d_in[9];
  const float* wmsg    = (const float*)d_in[10];
  const float* bmsg    = (const float*)d_in[11];
  const float* wupd    = (const float*)d_in[12];
  const float* bupd    = (const float*)d_in[13];
  const float* v2c_ln_g = (const float*)d_in[14];
  const float* v2c_ln_b = (const float*)d_in[15];
  const float* wc2v    = (const float*)d_in[16];
  const float* bc2v    = (const float*)d_in[17];
  const float* c2v_ln_g = (const float*)d_in[18];
  const float* c2v_ln_b = (const float*)d_in[19];
  const float* vgate_w = (const float*)d_in[20];
  const float* vgate_b = (const float*)d_in[21];
  const float* cgate_w = (const float*)d_in[22];
  const float* cgate_b = (const float*)d_in[23];
  const float* var_ln_g = (const float*)d_in[24];
  const float* var_ln_b = (const float*)d_in[25];
  const float* con_ln_g = (const float*)d_in[26];
  const float* con_ln_b = (const float*)d_in[27];
  float* hv = (float*)d_out;

  char* p = (char*)d_ws;
  auto carve = [&](size_t bytes) { char* r = p; p += (bytes + 255) & ~(size_t)255; return r; };
  int* cnt_c = (int*)carve((size_t)NCN*4);
  int* cur_c = (int*)carve((size_t)NCN*4);
  int* cnt_v = (int*)carve((size_t)NVN*4);
  int* cur_v = (int*)carve((size_t)NVN*4);
  int* off_c = (int*)carve((size_t)(NCN+1)*4);
  int* off_v = (int*)carve((size_t)(NVN+1)*4);
  int* aux   = (int*)carve(1024*4);
  int* lst_c = (int*)carve((size_t)NE*4);
  int* lst_v = (int*)carve((size_t)NE*4);
  float* wf  = (float*)carve((size_t)H*H*4);
  float* bfu = (float*)carve((size_t)H*4);
  unsigned short* wfph = (unsigned short*)carve((size_t)H*H*2);
  unsigned short* wfpl = (unsigned short*)carve((size_t)H*H*2);
  unsigned short* wvph = (unsigned short*)carve((size_t)H*H*2);
  unsigned short* wvpl = (unsigned short*)carve((size_t)H*H*2);
  unsigned short* cgph = (unsigned short*)carve((size_t)2*H*H*2);
  unsigned short* cgpl = (unsigned short*)carve((size_t)2*H*H*2);
  unsigned short* vgph = (unsigned short*)carve((size_t)2*H*H*2);
  unsigned short* vgpl = (unsigned short*)carve((size_t)2*H*H*2);
  float* hc    = (float*)carve((size_t)NCN*H*4);
  float* c_new = (float*)carve((size_t)NCN*H*4);
  float* v_new = (float*)carve((size_t)NVN*H*4);
  float* t_c   = (float*)carve((size_t)NCN*H*4);
  float* t_v   = (float*)carve((size_t)NVN*H*4);
  if ((size_t)(p - (char*)d_ws) > ws_size) return;

  (void)hipMemsetAsync(cnt_c, 0, (size_t)NCN*4, stream);
  (void)hipMemsetAsync(cur_c, 0, (size_t)NCN*4, stream);
  (void)hipMemsetAsync(cnt_v, 0, (size_t)NVN*4, stream);
  (void)hipMemsetAsync(cur_v, 0, (size_t)NVN*4, stream);

  k_fuse_w<<<64, 256, 0, stream>>>(wmsg, wupd, wf);
  k_fuse_b<<<1, 128, 0, stream>>>(bmsg, wupd, bfu);
  k_perm2<<<(H*H+255)/256, 256, 0, stream>>>(wf, wfph, wfpl, H);
  k_perm2<<<(H*H+255)/256, 256, 0, stream>>>(wc2v, wvph, wvpl, H);
  k_perm2<<<(2*H*H+255)/256, 256, 0, stream>>>(cgate_w, cgph, cgpl, 2*H);
  k_perm2<<<(2*H*H+255)/256, 256, 0, stream>>>(vgate_w, vgph, vgpl, 2*H);

  k_count<<<1024, 256, 0, stream>>>(evc_dst, ecv_dst, cnt_c, cnt_v);
  int nbc = (NCN + 255)/256, nbv = (NVN + 255)/256;
  k_scan1<<<nbc, 256, 0, stream>>>(cnt_c, off_c, aux, NCN);
  k_scan2<<<1, 1024, 0, stream>>>(aux, nbc);
  k_scan3<<<nbc, 256, 0, stream>>>(off_c, aux, NCN, NE);
  k_scan1<<<nbv, 256, 0, stream>>>(cnt_v, off_v, aux, NVN);
  k_scan2<<<1, 1024, 0, stream>>>(aux, nbv);
  k_scan3<<<nbv, 256, 0, stream>>>(off_v, aux, NVN, NE);
  k_scatter<<<1024, 256, 0, stream>>>(evc_src, evc_dst, ecv_src, ecv_dst,
                                      off_c, cur_c, lst_c, off_v, cur_v, lst_v);

  k_init_var<<<NVN/4, 256, 0, stream>>>(x_var, vproj_w, vproj_b, var_ln_g, var_ln_b, hv);
  k_init_con<<<NCN/4, 256, 0, stream>>>(x_con, cproj_w, cproj_b, con_ln_g, con_ln_b, hc);

  for (int r = 0; r < 2; ++r) {
    // ---- v2c ----
    k_gather<<<(NCN+3)/4, 256, 0, stream>>>(hv, off_c, lst_c, t_c, NCN);
    k_mm<<<(NCN+63)/64, 256, 0, stream>>>(t_c, wfph, wfpl, t_c, NCN);   // pre = mean @ Wf (in-place)
    k_con_epi<<<(NCN+3)/4, 256, 0, stream>>>(t_c, cnt_c, x_con, bfu, wupd, bupd,
                                             v2c_ln_g, v2c_ln_b, c_new);
    k_mm2<<<(NCN+63)/64, 256, 0, stream>>>(hc, c_new, cgph, cgpl, t_c, NCN);  // t = hc@G1 + c_new@G2
    k_gate<<<(NCN*H/4 + 255)/256, 256, 0, stream>>>(t_c, c_new, hc, cgate_b, NCN*H/4);
    // ---- c2v ----
    k_gather<<<(NVN+3)/4, 256, 0, stream>>>(hc, off_v, lst_v, t_v, NVN);
    k_mm<<<(NVN+63)/64, 256, 0, stream>>>(t_v, wvph, wvpl, t_v, NVN);   // pre2 = mean @ Wc2v
    k_var_epi<<<(NVN+3)/4, 256, 0, stream>>>(t_v, cnt_v, bc2v, c2v_ln_g, c2v_ln_b, v_new);
    k_mm2<<<(NVN+63)/64, 256, 0, stream>>>(hv, v_new, vgph, vgpl, t_v, NVN);  // t = hv@G1 + v_new@G2
    k_gate<<<(NVN*H/4 + 255)/256, 256, 0, stream>>>(t_v, v_new, hv, vgate_b, NVN*H/4);
  }
}

// Round 9
// 942.874 us; speedup vs baseline: 1.5814x; 1.0078x over previous
//
#include <hip/hip_runtime.h>
#include <stdint.h>

#define NVN 100000
#define NCN 50000
#define NE  800000
#define H   128

typedef __attribute__((ext_vector_type(8))) short bf16x8;
typedef __attribute__((ext_vector_type(4))) float f32x4;

static __device__ __forceinline__ float wredsum(float v) {
#pragma unroll
  for (int off = 32; off > 0; off >>= 1) v += __shfl_xor(v, off, 64);
  return v;
}
static __device__ __forceinline__ float sigmoidf(float x) { return 1.0f / (1.0f + __expf(-x)); }
static __device__ __forceinline__ unsigned short f2bf(float f) {
  unsigned int u = __float_as_uint(f);
  return (unsigned short)((u + 0x7FFFu + ((u >> 16) & 1u)) >> 16);  // RNE
}
static __device__ __forceinline__ short2 splitbf(float f) {
  unsigned short h = f2bf(f);
  float hf = __uint_as_float(((unsigned int)h) << 16);
  short2 r;
  r.x = (short)h;
  r.y = (short)f2bf(f - hf);
  return r;
}

// ---------------- init: h = LN(relu(x @ W + b)), writes f32 master + bf16 shadow ----------------
__global__ __launch_bounds__(256) void k_init_var(const float* __restrict__ xv,
    const float* __restrict__ w, const float* __restrict__ b,
    const float* __restrict__ g, const float* __restrict__ bb,
    float* __restrict__ hv, unsigned short* __restrict__ hb) {
  int wid = (blockIdx.x * 256 + threadIdx.x) >> 6;
  int lane = threadIdx.x & 63;
  if (wid >= NVN) return;
  float x0 = xv[wid*4+0], x1 = xv[wid*4+1], x2 = xv[wid*4+2], x3 = xv[wid*4+3];
  int c0 = lane, c1 = lane + 64;
  float v0 = b[c0] + x0*w[c0] + x1*w[H+c0] + x2*w[2*H+c0] + x3*w[3*H+c0];
  float v1 = b[c1] + x0*w[c1] + x1*w[H+c1] + x2*w[2*H+c1] + x3*w[3*H+c1];
  v0 = fmaxf(v0, 0.f); v1 = fmaxf(v1, 0.f);
  float mu = wredsum(v0 + v1) * (1.0f/H);
  float d0 = v0 - mu, d1 = v1 - mu;
  float var = wredsum(d0*d0 + d1*d1) * (1.0f/H);
  float r = rsqrtf(var + 1e-5f);
  float o0 = d0*r*g[c0] + bb[c0], o1 = d1*r*g[c1] + bb[c1];
  hv[(size_t)wid*H + c0] = o0;  hv[(size_t)wid*H + c1] = o1;
  hb[(size_t)wid*H + c0] = f2bf(o0);  hb[(size_t)wid*H + c1] = f2bf(o1);
}

__global__ __launch_bounds__(256) void k_init_con(const float* __restrict__ xc,
    const float* __restrict__ w, const float* __restrict__ b,
    const float* __restrict__ g, const float* __restrict__ bb,
    float* __restrict__ hc, unsigned short* __restrict__ hb) {
  int wid = (blockIdx.x * 256 + threadIdx.x) >> 6;
  int lane = threadIdx.x & 63;
  if (wid >= NCN) return;
  float x = xc[wid];
  int c0 = lane, c1 = lane + 64;
  float v0 = fmaxf(b[c0] + x*w[c0], 0.f);
  float v1 = fmaxf(b[c1] + x*w[c1], 0.f);
  float mu = wredsum(v0 + v1) * (1.0f/H);
  float d0 = v0 - mu, d1 = v1 - mu;
  float var = wredsum(d0*d0 + d1*d1) * (1.0f/H);
  float r = rsqrtf(var + 1e-5f);
  float o0 = d0*r*g[c0] + bb[c0], o1 = d1*r*g[c1] + bb[c1];
  hc[(size_t)wid*H + c0] = o0;  hc[(size_t)wid*H + c1] = o1;
  hb[(size_t)wid*H + c0] = f2bf(o0);  hb[(size_t)wid*H + c1] = f2bf(o1);
}

// ---------------- weight fusion ----------------
__global__ void k_fuse_w(const float* __restrict__ wm, const float* __restrict__ wu,
                         float* __restrict__ wf) {
  int idx = blockIdx.x*256 + threadIdx.x;   // 16384
  int i = idx >> 7, j = idx & 127;
  float a = 0.f;
  for (int k = 0; k < H; ++k) a = fmaf(wm[i*H+k], wu[k*H+j], a);
  wf[idx] = a;
}
__global__ void k_fuse_b(const float* __restrict__ bm, const float* __restrict__ wu,
                         float* __restrict__ bf) {
  int j = threadIdx.x;
  float a = 0.f;
  for (int k = 0; k < H; ++k) a = fmaf(bm[k], wu[k*H+j], a);
  bf[j] = a;
}

// ---------------- weight permutation into MFMA B-fragment order, hi+lo split ----------------
__global__ __launch_bounds__(256) void k_perm2(const float* __restrict__ W,
    unsigned short* __restrict__ Whi, unsigned short* __restrict__ Wlo, int K) {
  int idx = blockIdx.x*256 + threadIdx.x;
  if (idx >= K*H) return;
  int j = idx & 7, lane = (idx >> 3) & 63, ct = (idx >> 9) & 7, kb = idx >> 12;
  int k = kb*32 + (lane >> 4)*8 + j, c = ct*16 + (lane & 15);
  float w = W[k*H + c];
  unsigned short h = f2bf(w);
  float hf = __uint_as_float(((unsigned int)h) << 16);
  Whi[idx] = h;
  Wlo[idx] = f2bf(w - hf);
}

// ---------------- CSR build ----------------
__global__ void k_count(const int* __restrict__ dc, const int* __restrict__ dv,
                        int* __restrict__ cnt_c, int* __restrict__ cnt_v) {
  for (int e = blockIdx.x*blockDim.x + threadIdx.x; e < NE; e += gridDim.x*blockDim.x) {
    atomicAdd(&cnt_c[dc[e]], 1);
    atomicAdd(&cnt_v[dv[e]], 1);
  }
}
__global__ __launch_bounds__(256) void k_scan1(const int* __restrict__ in, int* __restrict__ out,
                                               int* __restrict__ aux, int n) {
  __shared__ int s[256];
  int t = threadIdx.x, i = blockIdx.x*256 + t;
  int v = (i < n) ? in[i] : 0;
  s[t] = v; __syncthreads();
  for (int off = 1; off < 256; off <<= 1) {
    int x = (t >= off) ? s[t - off] : 0;
    __syncthreads();
    s[t] += x;
    __syncthreads();
  }
  if (i < n) out[i] = s[t] - v;
  if (t == 255) aux[blockIdx.x] = s[255];
}
__global__ __launch_bounds__(1024) void k_scan2(int* __restrict__ aux, int nb) {
  __shared__ int s[1024];
  int t = threadIdx.x;
  int v = (t < nb) ? aux[t] : 0;
  s[t] = v; __syncthreads();
  for (int off = 1; off < 1024; off <<= 1) {
    int x = (t >= off) ? s[t-off] : 0;
    __syncthreads();
    s[t] += x;
    __syncthreads();
  }
  if (t < nb) aux[t] = s[t] - v;
}
__global__ __launch_bounds__(256) void k_scan3(int* __restrict__ out, const int* __restrict__ aux,
                                               int n, int total) {
  int i = blockIdx.x*256 + threadIdx.x;
  if (i < n) out[i] += aux[blockIdx.x];
  if (i == 0) out[n] = total;
}
__global__ void k_scatter(const int* __restrict__ sc, const int* __restrict__ dc,
                          const int* __restrict__ sv, const int* __restrict__ dv,
                          const int* __restrict__ off_c, int* __restrict__ cur_c, int* __restrict__ lst_c,
                          const int* __restrict__ off_v, int* __restrict__ cur_v, int* __restrict__ lst_v) {
  for (int e = blockIdx.x*blockDim.x + threadIdx.x; e < NE; e += gridDim.x*blockDim.x) {
    int d = dc[e]; int p = atomicAdd(&cur_c[d], 1); lst_c[off_c[d] + p] = sc[e];
    d = dv[e];     p = atomicAdd(&cur_v[d], 1);     lst_v[off_v[d] + p] = sv[e];
  }
}

// ---------------- gather from bf16 table, f32 accumulate, f32 out ----------------
__global__ __launch_bounds__(256) void k_gather_bf(const unsigned int* __restrict__ tab,
    const int* __restrict__ off, const int* __restrict__ lst,
    float* __restrict__ out, int n) {
  int wid = (blockIdx.x * 256 + threadIdx.x) >> 6;
  int lane = threadIdx.x & 63;
  if (wid >= n) return;
  int s0 = off[wid], s1 = off[wid+1];
  float a0 = 0.f, a1 = 0.f;
  for (int p = s0; p < s1; ++p) {
    int src = lst[p];
    unsigned int u = tab[(size_t)src * 64 + lane];
    a0 += __uint_as_float(u << 16);          // col 2*lane   (low half)
    a1 += __uint_as_float(u & 0xFFFF0000u);  // col 2*lane+1 (high half)
  }
  float inv = 1.0f / ((float)(s1 - s0) + 1e-6f);
  ((float2*)(out + (size_t)wid*H))[lane] = make_float2(a0*inv, a1*inv);
}

// ---------------- PURE MFMA matmul: OUT = A @ W (split-operand), no epilogue ----------------
__global__ __launch_bounds__(256) void k_mm(const float* __restrict__ A,
    const unsigned short* __restrict__ Wph, const unsigned short* __restrict__ Wpl,
    float* __restrict__ OUT, int n) {
  const int wv = threadIdx.x >> 6, lane = threadIdx.x & 63;
  const int rbase = blockIdx.x*64 + wv*16;
  if (rbase >= n) return;
  const int g = lane >> 4, c15 = lane & 15;
  int arow = rbase + c15; if (arow > n-1) arow = n-1;
  const float* Ar = A + (size_t)arow*H + g*8;
  bf16x8 ahi[4], alo[4];
#pragma unroll
  for (int kb = 0; kb < 4; ++kb) {
    float4 p0 = *(const float4*)(Ar + kb*32);
    float4 p1 = *(const float4*)(Ar + kb*32 + 4);
    bf16x8 h, l;
    short2 s;
    s = splitbf(p0.x); h[0] = s.x; l[0] = s.y;
    s = splitbf(p0.y); h[1] = s.x; l[1] = s.y;
    s = splitbf(p0.z); h[2] = s.x; l[2] = s.y;
    s = splitbf(p0.w); h[3] = s.x; l[3] = s.y;
    s = splitbf(p1.x); h[4] = s.x; l[4] = s.y;
    s = splitbf(p1.y); h[5] = s.x; l[5] = s.y;
    s = splitbf(p1.z); h[6] = s.x; l[6] = s.y;
    s = splitbf(p1.w); h[7] = s.x; l[7] = s.y;
    ahi[kb] = h; alo[kb] = l;
  }
  const bf16x8* Bph = (const bf16x8*)Wph;
  const bf16x8* Bpl = (const bf16x8*)Wpl;
  f32x4 zero = {0.f, 0.f, 0.f, 0.f};
  f32x4 acc[8];
#pragma unroll
  for (int ct = 0; ct < 8; ++ct) acc[ct] = zero;
#pragma unroll
  for (int kb = 0; kb < 4; ++kb)
#pragma unroll
    for (int ct = 0; ct < 8; ++ct) {
      bf16x8 bh = Bph[(kb*8+ct)*64 + lane];
      bf16x8 bl = Bpl[(kb*8+ct)*64 + lane];
      acc[ct] = __builtin_amdgcn_mfma_f32_16x16x32_bf16(ahi[kb], bh, acc[ct], 0, 0, 0);
      acc[ct] = __builtin_amdgcn_mfma_f32_16x16x32_bf16(alo[kb], bh, acc[ct], 0, 0, 0);
      acc[ct] = __builtin_amdgcn_mfma_f32_16x16x32_bf16(ahi[kb], bl, acc[ct], 0, 0, 0);
    }
#pragma unroll
  for (int r = 0; r < 4; ++r) {
    int rg = rbase + g*4 + r;
    if (rg >= n) continue;
    float* op = OUT + (size_t)rg*H + c15;
#pragma unroll
    for (int ct = 0; ct < 8; ++ct) op[ct*16] = acc[ct][r];
  }
}

// ---------------- MFMA concat-matmul + fused sigmoid-gate (per-element epilogue only) ----------------
// t = A1@W[:H] + A2@W[H:];  g = sig(t + gb);  Hm = g*A2 + (1-g)*Hm;  Hb = bf16(Hm)
__global__ __launch_bounds__(256) void k_mm2g(const float* __restrict__ A1,
    const float* __restrict__ A2,
    const unsigned short* __restrict__ Wph, const unsigned short* __restrict__ Wpl,
    const float* __restrict__ gb,
    float* __restrict__ Hm, unsigned short* __restrict__ Hb, int n) {
  const int wv = threadIdx.x >> 6, lane = threadIdx.x & 63;
  const int rbase = blockIdx.x*64 + wv*16;
  if (rbase >= n) return;
  const int g = lane >> 4, c15 = lane & 15;
  int arow = rbase + c15; if (arow > n-1) arow = n-1;
  const float* Ar1 = A1 + (size_t)arow*H + g*8;
  const float* Ar2 = A2 + (size_t)arow*H + g*8;
  bf16x8 ahi[8], alo[8];
#pragma unroll
  for (int kb = 0; kb < 8; ++kb) {
    const float* src = (kb < 4) ? (Ar1 + kb*32) : (Ar2 + (kb-4)*32);
    float4 p0 = *(const float4*)(src);
    float4 p1 = *(const float4*)(src + 4);
    bf16x8 h, l;
    short2 s;
    s = splitbf(p0.x); h[0] = s.x; l[0] = s.y;
    s = splitbf(p0.y); h[1] = s.x; l[1] = s.y;
    s = splitbf(p0.z); h[2] = s.x; l[2] = s.y;
    s = splitbf(p0.w); h[3] = s.x; l[3] = s.y;
    s = splitbf(p1.x); h[4] = s.x; l[4] = s.y;
    s = splitbf(p1.y); h[5] = s.x; l[5] = s.y;
    s = splitbf(p1.z); h[6] = s.x; l[6] = s.y;
    s = splitbf(p1.w); h[7] = s.x; l[7] = s.y;
    ahi[kb] = h; alo[kb] = l;
  }
  const bf16x8* Bph = (const bf16x8*)Wph;
  const bf16x8* Bpl = (const bf16x8*)Wpl;
  f32x4 zero = {0.f, 0.f, 0.f, 0.f};
  f32x4 acc[8];
#pragma unroll
  for (int ct = 0; ct < 8; ++ct) acc[ct] = zero;
#pragma unroll
  for (int kb = 0; kb < 8; ++kb)
#pragma unroll
    for (int ct = 0; ct < 8; ++ct) {
      bf16x8 bh = Bph[(kb*8+ct)*64 + lane];
      bf16x8 bl = Bpl[(kb*8+ct)*64 + lane];
      acc[ct] = __builtin_amdgcn_mfma_f32_16x16x32_bf16(ahi[kb], bh, acc[ct], 0, 0, 0);
      acc[ct] = __builtin_amdgcn_mfma_f32_16x16x32_bf16(alo[kb], bh, acc[ct], 0, 0, 0);
      acc[ct] = __builtin_amdgcn_mfma_f32_16x16x32_bf16(ahi[kb], bl, acc[ct], 0, 0, 0);
    }
  float gbv[8];
#pragma unroll
  for (int ct = 0; ct < 8; ++ct) gbv[ct] = gb[ct*16 + c15];
#pragma unroll
  for (int r = 0; r < 4; ++r) {
    int rg = rbase + g*4 + r;
    if (rg >= n) continue;
    const float* np = A2 + (size_t)rg*H + c15;
    float* hp = Hm + (size_t)rg*H + c15;
    unsigned short* hbp = Hb + (size_t)rg*H + c15;
#pragma unroll
    for (int ct = 0; ct < 8; ++ct) {
      float gg = sigmoidf(acc[ct][r] + gbv[ct]);
      float nv = np[ct*16], ov = hp[ct*16];
      float res = gg*nv + (1.f - gg)*ov;
      hp[ct*16] = res;
      hbp[ct*16] = f2bf(res);
    }
  }
}

// ---------------- con epilogue (proven SIMT) ----------------
__global__ __launch_bounds__(256) void k_con_epi(const float* __restrict__ t,
    const int* __restrict__ cnt, const float* __restrict__ xc,
    const float* __restrict__ bfu, const float* __restrict__ wu, const float* __restrict__ bu,
    const float* __restrict__ g, const float* __restrict__ bb, float* __restrict__ out) {
  int wid = (blockIdx.x*256 + threadIdx.x) >> 6, lane = threadIdx.x & 63;
  if (wid >= NCN) return;
  float cf = (float)cnt[wid];
  float scale = cf / (cf + 1e-6f);
  float clue = xc[wid];
  int c0 = lane, c1 = lane + 64;
  float v0 = t[(size_t)wid*H+c0] + scale*bfu[c0] + clue*wu[H*H + c0] + bu[c0];
  float v1 = t[(size_t)wid*H+c1] + scale*bfu[c1] + clue*wu[H*H + c1] + bu[c1];
  v0 = fmaxf(v0, 0.f); v1 = fmaxf(v1, 0.f);
  float mu = wredsum(v0 + v1) * (1.0f/H);
  float d0 = v0 - mu, d1 = v1 - mu;
  float var = wredsum(d0*d0 + d1*d1) * (1.0f/H);
  float r = rsqrtf(var + 1e-5f);
  out[(size_t)wid*H + c0] = d0*r*g[c0] + bb[c0];
  out[(size_t)wid*H + c1] = d1*r*g[c1] + bb[c1];
}

// ---------------- var epilogue (proven SIMT) ----------------
__global__ __launch_bounds__(256) void k_var_epi(const float* __restrict__ t,
    const int* __restrict__ cnt, const float* __restrict__ bc,
    const float* __restrict__ g, const float* __restrict__ bb, float* __restrict__ out) {
  int wid = (blockIdx.x*256 + threadIdx.x) >> 6, lane = threadIdx.x & 63;
  if (wid >= NVN) return;
  float cf = (float)cnt[wid];
  float scale = cf / (cf + 1e-6f);
  int c0 = lane, c1 = lane + 64;
  float v0 = fmaxf(t[(size_t)wid*H+c0] + scale*bc[c0], 0.f);
  float v1 = fmaxf(t[(size_t)wid*H+c1] + scale*bc[c1], 0.f);
  float mu = wredsum(v0 + v1) * (1.0f/H);
  float d0 = v0 - mu, d1 = v1 - mu;
  float var = wredsum(d0*d0 + d1*d1) * (1.0f/H);
  float r = rsqrtf(var + 1e-5f);
  out[(size_t)wid*H + c0] = d0*r*g[c0] + bb[c0];
  out[(size_t)wid*H + c1] = d1*r*g[c1] + bb[c1];
}

extern "C" void kernel_launch(void* const* d_in, const int* in_sizes, int n_in,
                              void* d_out, int out_size, void* d_ws, size_t ws_size,
                              hipStream_t stream) {
  const float* x_var   = (const float*)d_in[0];
  const float* x_con   = (const float*)d_in[1];
  const int*   evc_src = (const int*)d_in[2];
  const int*   evc_dst = (const int*)d_in[3];
  const int*   ecv_src = (const int*)d_in[4];
  const int*   ecv_dst = (const int*)d_in[5];
  const float* vproj_w = (const float*)d_in[6];
  const float* vproj_b = (const float*)d_in[7];
  const float* cproj_w = (const float*)d_in[8];
  const float* cproj_b = (const float*)d_in[9];
  const float* wmsg    = (const float*)d_in[10];
  const float* bmsg    = (const float*)d_in[11];
  const float* wupd    = (const float*)d_in[12];
  const float* bupd    = (const float*)d_in[13];
  const float* v2c_ln_g = (const float*)d_in[14];
  const float* v2c_ln_b = (const float*)d_in[15];
  const float* wc2v    = (const float*)d_in[16];
  const float* bc2v    = (const float*)d_in[17];
  const float* c2v_ln_g = (const float*)d_in[18];
  const float* c2v_ln_b = (const float*)d_in[19];
  const float* vgate_w = (const float*)d_in[20];
  const float* vgate_b = (const float*)d_in[21];
  const float* cgate_w = (const float*)d_in[22];
  const float* cgate_b = (const float*)d_in[23];
  const float* var_ln_g = (const float*)d_in[24];
  const float* var_ln_b = (const float*)d_in[25];
  const float* con_ln_g = (const float*)d_in[26];
  const float* con_ln_b = (const float*)d_in[27];
  float* hv = (float*)d_out;

  char* p = (char*)d_ws;
  auto carve = [&](size_t bytes) { char* r = p; p += (bytes + 255) & ~(size_t)255; return r; };
  int* cnt_c = (int*)carve((size_t)NCN*4);
  int* cur_c = (int*)carve((size_t)NCN*4);
  int* cnt_v = (int*)carve((size_t)NVN*4);
  int* cur_v = (int*)carve((size_t)NVN*4);
  int* off_c = (int*)carve((size_t)(NCN+1)*4);
  int* off_v = (int*)carve((size_t)(NVN+1)*4);
  int* aux   = (int*)carve(1024*4);
  int* lst_c = (int*)carve((size_t)NE*4);
  int* lst_v = (int*)carve((size_t)NE*4);
  float* wf  = (float*)carve((size_t)H*H*4);
  float* bfu = (float*)carve((size_t)H*4);
  unsigned short* wfph = (unsigned short*)carve((size_t)H*H*2);
  unsigned short* wfpl = (unsigned short*)carve((size_t)H*H*2);
  unsigned short* wvph = (unsigned short*)carve((size_t)H*H*2);
  unsigned short* wvpl = (unsigned short*)carve((size_t)H*H*2);
  unsigned short* cgph = (unsigned short*)carve((size_t)2*H*H*2);
  unsigned short* cgpl = (unsigned short*)carve((size_t)2*H*H*2);
  unsigned short* vgph = (unsigned short*)carve((size_t)2*H*H*2);
  unsigned short* vgpl = (unsigned short*)carve((size_t)2*H*H*2);
  float* hc    = (float*)carve((size_t)NCN*H*4);
  float* c_new = (float*)carve((size_t)NCN*H*4);
  float* v_new = (float*)carve((size_t)NVN*H*4);
  float* t_c   = (float*)carve((size_t)NCN*H*4);
  float* t_v   = (float*)carve((size_t)NVN*H*4);
  unsigned short* hvb = (unsigned short*)carve((size_t)NVN*H*2);
  unsigned short* hcb = (unsigned short*)carve((size_t)NCN*H*2);
  if ((size_t)(p - (char*)d_ws) > ws_size) return;

  (void)hipMemsetAsync(cnt_c, 0, (size_t)NCN*4, stream);
  (void)hipMemsetAsync(cur_c, 0, (size_t)NCN*4, stream);
  (void)hipMemsetAsync(cnt_v, 0, (size_t)NVN*4, stream);
  (void)hipMemsetAsync(cur_v, 0, (size_t)NVN*4, stream);

  k_fuse_w<<<64, 256, 0, stream>>>(wmsg, wupd, wf);
  k_fuse_b<<<1, 128, 0, stream>>>(bmsg, wupd, bfu);
  k_perm2<<<(H*H+255)/256, 256, 0, stream>>>(wf, wfph, wfpl, H);
  k_perm2<<<(H*H+255)/256, 256, 0, stream>>>(wc2v, wvph, wvpl, H);
  k_perm2<<<(2*H*H+255)/256, 256, 0, stream>>>(cgate_w, cgph, cgpl, 2*H);
  k_perm2<<<(2*H*H+255)/256, 256, 0, stream>>>(vgate_w, vgph, vgpl, 2*H);

  k_count<<<1024, 256, 0, stream>>>(evc_dst, ecv_dst, cnt_c, cnt_v);
  int nbc = (NCN + 255)/256, nbv = (NVN + 255)/256;
  k_scan1<<<nbc, 256, 0, stream>>>(cnt_c, off_c, aux, NCN);
  k_scan2<<<1, 1024, 0, stream>>>(aux, nbc);
  k_scan3<<<nbc, 256, 0, stream>>>(off_c, aux, NCN, NE);
  k_scan1<<<nbv, 256, 0, stream>>>(cnt_v, off_v, aux, NVN);
  k_scan2<<<1, 1024, 0, stream>>>(aux, nbv);
  k_scan3<<<nbv, 256, 0, stream>>>(off_v, aux, NVN, NE);
  k_scatter<<<1024, 256, 0, stream>>>(evc_src, evc_dst, ecv_src, ecv_dst,
                                      off_c, cur_c, lst_c, off_v, cur_v, lst_v);

  k_init_var<<<NVN/4, 256, 0, stream>>>(x_var, vproj_w, vproj_b, var_ln_g, var_ln_b, hv, hvb);
  k_init_con<<<NCN/4, 256, 0, stream>>>(x_con, cproj_w, cproj_b, con_ln_g, con_ln_b, hc, hcb);

  for (int r = 0; r < 2; ++r) {
    // ---- v2c ----
    k_gather_bf<<<(NCN+3)/4, 256, 0, stream>>>((const unsigned int*)hvb, off_c, lst_c, t_c, NCN);
    k_mm<<<(NCN+63)/64, 256, 0, stream>>>(t_c, wfph, wfpl, t_c, NCN);   // pre = mean @ Wf (in-place)
    k_con_epi<<<(NCN+3)/4, 256, 0, stream>>>(t_c, cnt_c, x_con, bfu, wupd, bupd,
                                             v2c_ln_g, v2c_ln_b, c_new);
    k_mm2g<<<(NCN+63)/64, 256, 0, stream>>>(hc, c_new, cgph, cgpl, cgate_b, hc, hcb, NCN);
    // ---- c2v ----
    k_gather_bf<<<(NVN+3)/4, 256, 0, stream>>>((const unsigned int*)hcb, off_v, lst_v, t_v, NVN);
    k_mm<<<(NVN+63)/64, 256, 0, stream>>>(t_v, wvph, wvpl, t_v, NVN);   // pre2 = mean @ Wc2v
    k_var_epi<<<(NVN+3)/4, 256, 0, stream>>>(t_v, cnt_v, bc2v, c2v_ln_g, c2v_ln_b, v_new);
    k_mm2g<<<(NVN+63)/64, 256, 0, stream>>>(hv, v_new, vgph, vgpl, vgate_b, hv, hvb, NVN);
  }
}